// Round 4
// baseline (243.520 us; speedup 1.0000x reference)
//
#include <hip/hip_runtime.h>
#include <hip/hip_bf16.h>

// Block_45810121179249: 2x (single-head attn + residual + LayerNorm)
// B=4, S=4096, E=256. FP32 in/out; proj bf16 MFMA; attention MX-fp8 MFMA.
//
// Round 15: attn de-convoyed.
// (a) Fused MFMA cluster: each iter issues S^T(kt+1) + PV(kt) back-to-back
//     right after the barrier; softmax(kt+1) moved to iteration END so it
//     overlaps the PV drain (softmax only depends on the S^T half, which
//     retires first). Kills the matrix-pipe idle gap during softmax.
//     V staged one tile behind K; single barrier/iter. Per-iter LDS hazard
//     table: writes {Kt[kt&1], Vt[(kt+1)&1]}, reads {Kt[(kt+1)&1], Vt[kt&1]}
//     -> disjoint; all waves between the same barriers.
// (b) exp2f -> __builtin_amdgcn_exp2f (raw v_exp_f32, 1 instr vs libm's
//     multi-instr fixup): ~32 fewer VALU-instr bursts per iter.

typedef __attribute__((ext_vector_type(8))) short bf16x8;
typedef __attribute__((ext_vector_type(4))) float f32x4;
typedef __attribute__((ext_vector_type(16))) float f32x16;
typedef __attribute__((ext_vector_type(4))) int i32x4;
typedef __attribute__((ext_vector_type(8))) int i32x8;
typedef unsigned char u8;

#define MFMA_BF16(A, B, C) __builtin_amdgcn_mfma_f32_16x16x32_bf16(A, B, C, 0, 0, 0)
// block-scaled fp8 MFMA, formats fp8e4m3/fp8e4m3, per-lane e8m0 scales
#define MFMA_SC(A, B, C, SA, SB)                                                \
    __builtin_amdgcn_mfma_scale_f32_32x32x64_f8f6f4(A, B, C, 0, 0, 0, SA, 0, SB)
#define SCALE_1  0x7F7F7F7Fu   // e8m0 127 = 2^0
#define SCALE_Q  0x79797979u   // e8m0 121 = 2^-6  (1/sqrt(4096))

#define CP16(g, l)                                                              \
    __builtin_amdgcn_global_load_lds(                                           \
        (const __attribute__((address_space(1))) void*)(g),                     \
        (__attribute__((address_space(3))) void*)(l), 16, 0, 0)

#if __has_builtin(__builtin_amdgcn_exp2f)
static __device__ __forceinline__ float fexp2(float x) {
    return __builtin_amdgcn_exp2f(x);
}
#else
static __device__ __forceinline__ float fexp2(float x) {
    float r;
    asm("v_exp_f32 %0, %1" : "=v"(r) : "v"(x));
    return r;
}
#endif

static __device__ __forceinline__ short f2bf(float f) {
    __hip_bfloat16 h = __float2bfloat16(f);
    return __builtin_bit_cast(short, h);
}
static __device__ __forceinline__ float bf2f(short s) {
    unsigned int u = ((unsigned int)(unsigned short)s) << 16;
    return __builtin_bit_cast(float, u);
}
static __device__ __forceinline__ float ld1(const float* p) { return *p; }
static __device__ __forceinline__ float ld1(const short* p) { return bf2f(*p); }
static __device__ __forceinline__ void st1(float* p, float v) { *p = v; }
static __device__ __forceinline__ void st1(short* p, float v) { *p = f2bf(v); }

static __device__ __forceinline__ u8 f2fp8(float f) {
    return (u8)(__builtin_amdgcn_cvt_pk_fp8_f32(f, f, 0, false) & 0xff);
}
static __device__ __forceinline__ unsigned int pk4fp8(float a, float b, float c, float d) {
    int w = __builtin_amdgcn_cvt_pk_fp8_f32(a, b, 0, false);
    w = __builtin_amdgcn_cvt_pk_fp8_f32(c, d, w, true);
    return (unsigned int)w;
}

static __device__ __forceinline__ bf16x8 ldA8(const short* p) {
    return *reinterpret_cast<const bf16x8*>(p);
}
static __device__ __forceinline__ bf16x8 ldA8(const float* p) {
    float4 f0 = *reinterpret_cast<const float4*>(p);
    float4 f1 = *reinterpret_cast<const float4*>(p + 4);
    bf16x8 r;
    r[0] = f2bf(f0.x); r[1] = f2bf(f0.y); r[2] = f2bf(f0.z); r[3] = f2bf(f0.w);
    r[4] = f2bf(f1.x); r[5] = f2bf(f1.y); r[6] = f2bf(f1.z); r[7] = f2bf(f1.w);
    return r;
}

static __device__ __forceinline__ i32x8 cat(i32x4 lo, i32x4 hi) {
    i32x8 r;
    r[0] = lo[0]; r[1] = lo[1]; r[2] = lo[2]; r[3] = lo[3];
    r[4] = hi[0]; r[5] = hi[1]; r[6] = hi[2]; r[7] = hi[3];
    return r;
}

// ---- staging: proj W tiles (256 thr, bf16 rows of 512 B) -------------------
template <int NCH256>
static __device__ __forceinline__ void stage_rows(const short* __restrict__ g,
                                                  short* s, int tid) {
    const int wave = tid >> 6;
#pragma unroll
    for (int j = 0; j < NCH256; ++j) {
        const int idx = j * 256 + tid;
        const int row = idx >> 5, c = idx & 31;
        CP16(g + row * 256 + ((c ^ (row & 7)) << 3),
             s + ((j * 256 + wave * 64) << 3));
    }
}
// ---- staging: attn K tile (fp8, 64 keys x 256 B, global pre-swizzled) ------
static __device__ __forceinline__ void stage_k(const u8* __restrict__ g,
                                               u8* s, int tid) {
    const int wave = tid >> 6;
#pragma unroll
    for (int j = 0; j < 4; ++j) {
        const int idx = j * 256 + tid;
        CP16(g + (idx << 4), s + ((j * 256 + wave * 64) << 4));
    }
}
// ---- staging: attn V tile (fp8, 256 e x 64 keys, global pre-swizzled) ------
static __device__ __forceinline__ void stage_v(const u8* __restrict__ g,
                                               u8* s, int tid) {
    const int wave = tid >> 6;
#pragma unroll
    for (int j = 0; j < 4; ++j) {
        const int idx = j * 256 + tid;
        CP16(g + ((idx >> 2) * 4096) + ((idx & 3) << 4),
             s + ((j * 256 + wave * 64) << 4));
    }
}

// ---------------- fp32 -> bf16 weight conversion (6 x 65536) ----------------
__global__ __launch_bounds__(256) void cvt_w_kernel(
    const float* __restrict__ w0, const float* __restrict__ w1,
    const float* __restrict__ w2, const float* __restrict__ w3,
    const float* __restrict__ w4, const float* __restrict__ w5,
    short* __restrict__ wb)
{
    const int idx = (blockIdx.x * 256 + threadIdx.x) * 8;   // grid 192 -> exact
    const int w = idx >> 16, off = idx & 65535;
    const float* src = w0;
    if (w == 1) src = w1;
    else if (w == 2) src = w2;
    else if (w == 3) src = w3;
    else if (w == 4) src = w4;
    else if (w == 5) src = w5;
    *reinterpret_cast<bf16x8*>(wb + w * 65536 + off) = ldA8(src + off);
}

// ---------------- QKV projection (bf16 MFMA), fp8 outputs, un-fused ---------
// grid (256, 3): x = 64-row token tile, y = {Q,K,V}. 3 concurrent blocks/CU.
// Q pre-scaled by log2(e); K and V written in the attn-LDS layouts.
template <typename TX>
__global__ __launch_bounds__(256, 2) void qkv_proj_kernel(
    const TX* __restrict__ X, const short* __restrict__ Wb,
    const float* __restrict__ bq, const float* __restrict__ bk,
    const float* __restrict__ bv,
    u8* __restrict__ Qo, u8* __restrict__ Ko, u8* __restrict__ VTo)
{
    __shared__ __attribute__((aligned(16))) short Wt[128 * 256];  // 64 KB half
    const int tid  = threadIdx.x;
    const int lane = tid & 63;
    const int wave = tid >> 6;
    const int c16  = lane & 15;
    const int quad = lane >> 4;
    const int which = blockIdx.y;
    const int m0 = blockIdx.x * 64 + wave * 16;

    const short* W    = Wb + which * 65536;
    const float* bias = (which == 0) ? bq : (which == 1) ? bk : bv;

    bf16x8 a[8];
#pragma unroll
    for (int ke = 0; ke < 8; ++ke)
        a[ke] = ldA8(X + (m0 + c16) * 256 + ke * 32 + quad * 8);

    f32x4 acc[16];
#pragma unroll
    for (int nb = 0; nb < 16; ++nb) { f32x4 z = {0.f, 0.f, 0.f, 0.f}; acc[nb] = z; }

#pragma unroll
    for (int half = 0; half < 2; ++half) {
        if (half) __syncthreads();
        stage_rows<16>(W + half * 128 * 256, Wt, tid);
        __syncthreads();
#pragma unroll
        for (int nb8 = 0; nb8 < 8; ++nb8) {
            const int nb = half * 8 + nb8;
            const short* wr = Wt + (nb8 * 16 + c16) * 256;
#pragma unroll
            for (int ke = 0; ke < 8; ++ke) {
                bf16x8 b = *reinterpret_cast<const bf16x8*>(
                    wr + (((ke * 4 + quad) ^ (c16 & 7)) << 3));
                acc[nb] = MFMA_BF16(a[ke], b, acc[nb]);
            }
        }
    }

    if (which == 0) {
        // Q: byte-linear [token][e], pre-scaled by log2(e)
        constexpr float L2E = 1.4426950408889634f;
#pragma unroll
        for (int nb = 0; nb < 16; ++nb) {
            const int o = nb * 16 + c16;
            const float bb_ = bias[o];
#pragma unroll
            for (int r = 0; r < 4; ++r)
                Qo[(m0 + quad * 4 + r) * 256 + o] = f2fp8((acc[nb][r] + bb_) * L2E);
        }
    } else if (which == 1) {
        // K: 16B unit u=o>>4 of key row stored at position u^(row&15)
#pragma unroll
        for (int nb = 0; nb < 16; ++nb) {
            const int o = nb * 16 + c16;   // o>>4 = nb, o&15 = c16
            const float bb_ = bias[o];
#pragma unroll
            for (int r = 0; r < 4; ++r) {
                const int row = m0 + quad * 4 + r;
                Ko[row * 256 + (((nb ^ (row & 15)) << 4) | c16)] =
                    f2fp8(acc[nb][r] + bb_);
            }
        }
    } else {
        // V^T: [e][4096 keys]; within each 64-key group, 16B unit
        // j=(n>>4)&3 stored at slot (j^((o>>1)&3))
#pragma unroll
        for (int nb = 0; nb < 16; ++nb) {
            const int o = nb * 16 + c16;
            const float bb_ = bias[o];
            const int row = m0 + quad * 4;
            const int batch = row >> 12;
            const int n = row & 4095;
            const int nsw = (n & ~63) | ((((n >> 4) ^ (o >> 1)) & 3) << 4) |
                            (n & 12);
            unsigned int pk = pk4fp8(acc[nb][0] + bb_, acc[nb][1] + bb_,
                                     acc[nb][2] + bb_, acc[nb][3] + bb_);
            *reinterpret_cast<unsigned int*>(
                VTo + (size_t)batch * (256 * 4096) + o * 4096 + nsw) = pk;
        }
    }
}

// ---------------- split-K flash attention partial (MX-fp8 32x32x64) ---------
// grid 512: combo = ((bi&7)<<1)|(bi>>8) -> 2 (batch,ks) pairs per XCD;
// qt = (bi>>3)&31. Block 256 thr = 4 waves x 32 q-rows; BK=64, 16 iters;
// K,V fp8 double-buffered in LDS (64 KB). 2 blocks/CU, 2 waves/SIMD.
// Fused-cluster pipeline: per iter [bar | stage | S^T(kt+1)+PV(kt) MFMA
// cluster | softmax(kt+1)]. V staged one tile behind K.
__global__ __launch_bounds__(256, 2) void attn_part_kernel(
    const u8* __restrict__ Qb, const u8* __restrict__ Kb,
    const u8* __restrict__ VTb,
    short* __restrict__ Op, float* __restrict__ Lo)
{
    __shared__ __attribute__((aligned(16))) u8 Kt[2][64 * 256];   // 2x16 KB
    __shared__ __attribute__((aligned(16))) u8 Vt[2][256 * 64];   // 2x16 KB

    const int tid  = threadIdx.x;
    const int lane = tid & 63;
    const int wave = tid >> 6;
    const int l31  = lane & 31;
    const int hi   = lane >> 5;
    const int c16  = lane & 15;
    const int bi = blockIdx.x;
    const int combo = ((bi & 7) << 1) | (bi >> 8);
    const int batch = combo >> 2;
    const int ks    = combo & 3;
    const int qt    = (bi >> 3) & 31;
    const size_t bb = (size_t)batch * (4096 * 256);
    const int rw = qt * 128 + wave * 32;          // wave's 32 q rows
    const int kbase = ks * 1024;

    // Q fragments (B operand): Q[q=l31][e = ke*64 + hi*32 + 0..31]
    i32x8 qf[4];
#pragma unroll
    for (int ke = 0; ke < 4; ++ke) {
        const u8* qp = Qb + bb + (rw + l31) * 256 + ke * 64 + hi * 32;
        qf[ke] = cat(*reinterpret_cast<const i32x4*>(qp),
                     *reinterpret_cast<const i32x4*>(qp + 16));
    }

    f32x16 z16;
#pragma unroll
    for (int i = 0; i < 16; ++i) z16[i] = 0.f;
    f32x16 oa[8];
#pragma unroll
    for (int et = 0; et < 8; ++et) oa[et] = z16;
    f32x16 lacc = z16;                 // row-sums via ones-MFMA

    i32x8 onesf;                       // fp8 e4m3 1.0 = 0x38, splat
#pragma unroll
    for (int i = 0; i < 8; ++i) onesf[i] = 0x38383838;

    // lane-constant LDS read offsets (all 2-way max per quarter-wave = free)
    int kx0[4], kx1[4];
#pragma unroll
    for (int ke = 0; ke < 4; ++ke) {
        kx0[ke] = ((ke * 4 + hi * 2) ^ c16) << 4;
        kx1[ke] = ((ke * 4 + hi * 2 + 1) ^ c16) << 4;
    }
    const int vsw = (l31 >> 1) & 3;
    const int vx0 = ((hi * 2) ^ vsw) << 4;
    const int vx1 = ((hi * 2 + 1) ^ vsw) << 4;

    const u8* Kg = Kb + bb + kbase * 256;
    const u8* Vg = VTb + bb + kbase;

    f32x16 s0, s1;
    i32x8 pf;

    auto do_st = [&](const u8* K) {           // S^T: 16 b128 reads + 8 MFMA
        const u8* kp = K + l31 * 256;
        __builtin_amdgcn_s_setprio(1);
#pragma unroll
        for (int ke = 0; ke < 4; ++ke) {
            i32x8 a0 = cat(*reinterpret_cast<const i32x4*>(kp + kx0[ke]),
                           *reinterpret_cast<const i32x4*>(kp + kx1[ke]));
            s0 = (ke == 0) ? MFMA_SC(a0, qf[0], z16, SCALE_1, SCALE_Q)
                           : MFMA_SC(a0, qf[ke], s0, SCALE_1, SCALE_Q);
            i32x8 a1 = cat(*reinterpret_cast<const i32x4*>(kp + 8192 + kx0[ke]),
                           *reinterpret_cast<const i32x4*>(kp + 8192 + kx1[ke]));
            s1 = (ke == 0) ? MFMA_SC(a1, qf[0], z16, SCALE_1, SCALE_Q)
                           : MFMA_SC(a1, qf[ke], s1, SCALE_1, SCALE_Q);
        }
        __builtin_amdgcn_s_setprio(0);
    };
    auto do_softmax = [&]() {                 // s0,s1 -> pf (fp8 P-fragment)
        unsigned int dw0[4], dw1[4];
#pragma unroll
        for (int g = 0; g < 4; ++g) {
            const float p00 = fexp2(s0[4 * g + 0]);
            const float p01 = fexp2(s0[4 * g + 1]);
            const float p02 = fexp2(s0[4 * g + 2]);
            const float p03 = fexp2(s0[4 * g + 3]);
            const float p10 = fexp2(s1[4 * g + 0]);
            const float p11 = fexp2(s1[4 * g + 1]);
            const float p12 = fexp2(s1[4 * g + 2]);
            const float p13 = fexp2(s1[4 * g + 3]);
            dw0[g] = pk4fp8(p00, p01, p02, p03);
            dw1[g] = pk4fp8(p10, p11, p12, p13);
        }
#pragma unroll
        for (int g = 0; g < 4; ++g)
            asm volatile("v_permlane32_swap_b32 %0, %1"
                         : "+v"(dw0[g]), "+v"(dw1[g]));
        pf[0] = (int)dw0[0]; pf[1] = (int)dw1[0];
        pf[2] = (int)dw0[1]; pf[3] = (int)dw1[1];
        pf[4] = (int)dw0[2]; pf[5] = (int)dw1[2];
        pf[6] = (int)dw0[3]; pf[7] = (int)dw1[3];
    };

    // ---- prologue: tile 0 resident; S^T(0); softmax(0); K(1) in flight ----
    stage_k(Kg, &Kt[0][0], tid);
    stage_v(Vg, &Vt[0][0], tid);
    __syncthreads();
    stage_k(Kg + 64 * 256, &Kt[1][0], tid);
    do_st(&Kt[0][0]);
    do_softmax();

    for (int kt = 0; kt < 16; ++kt) {
        __syncthreads();   // [D] K(kt+1), V(kt) resident; buffers flip-safe
        if (kt + 2 < 16)   // [E] stage into parities not read this iter
            stage_k(Kg + (kt + 2) * 64 * 256, &Kt[kt & 1][0], tid);
        if (kt + 1 < 16)
            stage_v(Vg + (kt + 1) * 64, &Vt[(kt + 1) & 1][0], tid);

        // [B] fused MFMA cluster: S^T(kt+1) first (softmax dep), PV(kt) after
        if (kt + 1 < 16)
            do_st(&Kt[(kt + 1) & 1][0]);

        {
            const u8* V = &Vt[kt & 1][0];
            __builtin_amdgcn_s_setprio(1);
#pragma unroll
            for (int et = 0; et < 8; ++et) {
                const u8* vp = V + (et * 32 + l31) * 64;
                i32x8 b = cat(*reinterpret_cast<const i32x4*>(vp + vx0),
                              *reinterpret_cast<const i32x4*>(vp + vx1));
                oa[et] = MFMA_SC(pf, b, oa[et], SCALE_1, SCALE_1);
            }
            lacc = MFMA_SC(pf, onesf, lacc, SCALE_1, SCALE_1);
            __builtin_amdgcn_s_setprio(0);
        }

        // [C] softmax(kt+1): overlaps PV drain (dep = S^T regs only)
        if (kt + 1 < 16)
            do_softmax();
    }

    // ---- epilogue: write O partial + l (from lacc; cols are redundant) ----
    const size_t base = (size_t)ks * 16384 + batch * 4096 + rw;
#pragma unroll
    for (int et = 0; et < 8; ++et)
#pragma unroll
        for (int r = 0; r < 16; ++r) {
            const int qr = (r & 3) + 8 * (r >> 2) + 4 * hi;
            Op[(base + qr) * 256 + et * 32 + l31] = f2bf(oa[et][r]);
        }
    if (l31 == 0) {
#pragma unroll
        for (int r = 0; r < 16; ++r) {
            const int qr = (r & 3) + 8 * (r >> 2) + 4 * hi;
            Lo[base + qr] = lacc[r];
        }
    }
}

// ---------------- merge splits + residual + LayerNorm ----------------
template <typename TRES, typename TOUT>
__global__ __launch_bounds__(256) void merge_ln_kernel(
    const short* __restrict__ Op, const float* __restrict__ Lo,
    const TRES* __restrict__ res, const float* __restrict__ gamma,
    const float* __restrict__ beta, TOUT* __restrict__ out)
{
    const int lane = threadIdx.x & 63;
    const int wave = threadIdx.x >> 6;
    const int row = blockIdx.x * 4 + wave;          // batch*4096 + local row
    const float li = 1.0f / (Lo[row] + Lo[16384 + row] +
                             Lo[32768 + row] + Lo[49152 + row]);
    const int e = lane * 4;
    float o[4] = {0.f, 0.f, 0.f, 0.f};
#pragma unroll
    for (int s = 0; s < 4; ++s) {
        ushort4 u = *reinterpret_cast<const ushort4*>(
            Op + ((size_t)s * 16384 + row) * 256 + e);
        o[0] += bf2f((short)u.x);
        o[1] += bf2f((short)u.y);
        o[2] += bf2f((short)u.z);
        o[3] += bf2f((short)u.w);
    }
    float y[4];
#pragma unroll
    for (int i = 0; i < 4; ++i)
        y[i] = o[i] * li + ld1(res + (size_t)row * 256 + e + i);

    float sum = y[0] + y[1] + y[2] + y[3];
    float sq  = y[0]*y[0] + y[1]*y[1] + y[2]*y[2] + y[3]*y[3];
#pragma unroll
    for (int d = 1; d < 64; d <<= 1) {
        sum += __shfl_xor(sum, d, 64);
        sq  += __shfl_xor(sq,  d, 64);
    }
    const float mean = sum * (1.0f / 256.0f);
    const float var  = sq * (1.0f / 256.0f) - mean * mean;
    const float rstd = rsqrtf(var + 1e-5f);
#pragma unroll
    for (int i = 0; i < 4; ++i)
        st1(out + (size_t)row * 256 + e + i,
            (y[i] - mean) * rstd * gamma[e + i] + beta[e + i]);
}

extern "C" void kernel_launch(void* const* d_in, const int* in_sizes, int n_in,
                              void* d_out, int out_size, void* d_ws, size_t ws_size,
                              hipStream_t stream) {
    const float* x   = (const float*)d_in[0];
    const float* Wq1 = (const float*)d_in[1];
    const float* bq1 = (const float*)d_in[2];
    const float* Wk1 = (const float*)d_in[3];
    const float* bk1 = (const float*)d_in[4];
    const float* Wv1 = (const float*)d_in[5];
    const float* bv1 = (const float*)d_in[6];
    const float* Wq2 = (const float*)d_in[7];
    const float* bq2 = (const float*)d_in[8];
    const float* Wk2 = (const float*)d_in[9];
    const float* bk2 = (const float*)d_in[10];
    const float* Wv2 = (const float*)d_in[11];
    const float* bv2 = (const float*)d_in[12];
    const float* g1  = (const float*)d_in[13];
    const float* be1 = (const float*)d_in[14];
    const float* g2  = (const float*)d_in[15];
    const float* be2 = (const float*)d_in[16];

    const size_t NE = (size_t)16384 * 256;   // 4,194,304
    short* O1  = (short*)d_ws;               // 8 MB (layer-1 output, bf16)
    short* Wb  = O1 + NE;                    // 6 x 65536 bf16
    u8*    Qb  = (u8*)(Wb + 6 * 65536);      // fp8, 4 MB
    u8*    Kb  = Qb + NE;                    // fp8, 4 MB
    u8*    VTb = Kb + NE;                    // fp8, 4 MB
    short* Op  = (short*)(VTb + NE);         // 4 x 16384 x 256 bf16 = 32 MB
    float* Lo  = (float*)(Op + 4 * NE);      // 4 x 16384 fp32
    float* outp = (float*)d_out;

    dim3 pgrid(256, 3), pblk(256);

    cvt_w_kernel<<<192, 256, 0, stream>>>(Wq1, Wk1, Wv1, Wq2, Wk2, Wv2, Wb);

    qkv_proj_kernel<float><<<pgrid, pblk, 0, stream>>>(
        x, Wb, bq1, bk1, bv1, Qb, Kb, VTb);
    attn_part_kernel<<<512, 256, 0, stream>>>(Qb, Kb, VTb, Op, Lo);
    merge_ln_kernel<float, short><<<4096, 256, 0, stream>>>(Op, Lo, x, g1, be1, O1);

    qkv_proj_kernel<short><<<pgrid, pblk, 0, stream>>>(
        O1, Wb + 3 * 65536, bq2, bk2, bv2, Qb, Kb, VTb);
    attn_part_kernel<<<512, 256, 0, stream>>>(Qb, Kb, VTb, Op, Lo);
    merge_ln_kernel<short, float><<<4096, 256, 0, stream>>>(Op, Lo, O1, g2, be2, outp);
}

// Round 5
// 226.909 us; speedup vs baseline: 1.0732x; 1.0732x over previous
//
#include <hip/hip_runtime.h>
#include <hip/hip_bf16.h>

// Block_45810121179249: 2x (single-head attn + residual + LayerNorm)
// B=4, S=4096, E=256. FP32 in/out; proj bf16 MFMA; attention MX-fp8 MFMA.
//
// Round 16: r14 schedule (proven 48.6 us) + raw v_exp_f32 (proven -8.3 us
// VALU in r15's counters). r15's fused-MFMA-cluster reorder is REVERTED
// (it grew neither-pipe-idle by +15 us and HBM traffic by +13 MB).
// Attn loop per iter: softmax(kt) | PV(kt) | barrier | stage(kt+2) |
// S^T(kt+1). Hazards: stage writes buf[kt&1], S^T reads buf[(kt+1)&1],
// PV(kt) read Vt[kt&1] before the barrier -> disjoint/ordered. Tile kt+1
// readiness covered by the barrier's vmcnt(0) drain (loads one iter old).

typedef __attribute__((ext_vector_type(8))) short bf16x8;
typedef __attribute__((ext_vector_type(4))) float f32x4;
typedef __attribute__((ext_vector_type(16))) float f32x16;
typedef __attribute__((ext_vector_type(4))) int i32x4;
typedef __attribute__((ext_vector_type(8))) int i32x8;
typedef unsigned char u8;

#define MFMA_BF16(A, B, C) __builtin_amdgcn_mfma_f32_16x16x32_bf16(A, B, C, 0, 0, 0)
// block-scaled fp8 MFMA, formats fp8e4m3/fp8e4m3, per-lane e8m0 scales
#define MFMA_SC(A, B, C, SA, SB)                                                \
    __builtin_amdgcn_mfma_scale_f32_32x32x64_f8f6f4(A, B, C, 0, 0, 0, SA, 0, SB)
#define SCALE_1  0x7F7F7F7Fu   // e8m0 127 = 2^0
#define SCALE_Q  0x79797979u   // e8m0 121 = 2^-6  (1/sqrt(4096))

#define CP16(g, l)                                                              \
    __builtin_amdgcn_global_load_lds(                                           \
        (const __attribute__((address_space(1))) void*)(g),                     \
        (__attribute__((address_space(3))) void*)(l), 16, 0, 0)

static __device__ __forceinline__ float fexp2(float x) {
    float r;
    asm("v_exp_f32 %0, %1" : "=v"(r) : "v"(x));
    return r;
}

static __device__ __forceinline__ short f2bf(float f) {
    __hip_bfloat16 h = __float2bfloat16(f);
    return __builtin_bit_cast(short, h);
}
static __device__ __forceinline__ float bf2f(short s) {
    unsigned int u = ((unsigned int)(unsigned short)s) << 16;
    return __builtin_bit_cast(float, u);
}
static __device__ __forceinline__ float ld1(const float* p) { return *p; }
static __device__ __forceinline__ float ld1(const short* p) { return bf2f(*p); }
static __device__ __forceinline__ void st1(float* p, float v) { *p = v; }
static __device__ __forceinline__ void st1(short* p, float v) { *p = f2bf(v); }

static __device__ __forceinline__ u8 f2fp8(float f) {
    return (u8)(__builtin_amdgcn_cvt_pk_fp8_f32(f, f, 0, false) & 0xff);
}
static __device__ __forceinline__ unsigned int pk4fp8(float a, float b, float c, float d) {
    int w = __builtin_amdgcn_cvt_pk_fp8_f32(a, b, 0, false);
    w = __builtin_amdgcn_cvt_pk_fp8_f32(c, d, w, true);
    return (unsigned int)w;
}

static __device__ __forceinline__ bf16x8 ldA8(const short* p) {
    return *reinterpret_cast<const bf16x8*>(p);
}
static __device__ __forceinline__ bf16x8 ldA8(const float* p) {
    float4 f0 = *reinterpret_cast<const float4*>(p);
    float4 f1 = *reinterpret_cast<const float4*>(p + 4);
    bf16x8 r;
    r[0] = f2bf(f0.x); r[1] = f2bf(f0.y); r[2] = f2bf(f0.z); r[3] = f2bf(f0.w);
    r[4] = f2bf(f1.x); r[5] = f2bf(f1.y); r[6] = f2bf(f1.z); r[7] = f2bf(f1.w);
    return r;
}

static __device__ __forceinline__ i32x8 cat(i32x4 lo, i32x4 hi) {
    i32x8 r;
    r[0] = lo[0]; r[1] = lo[1]; r[2] = lo[2]; r[3] = lo[3];
    r[4] = hi[0]; r[5] = hi[1]; r[6] = hi[2]; r[7] = hi[3];
    return r;
}

// ---- staging: proj W tiles (256 thr, bf16 rows of 512 B) -------------------
template <int NCH256>
static __device__ __forceinline__ void stage_rows(const short* __restrict__ g,
                                                  short* s, int tid) {
    const int wave = tid >> 6;
#pragma unroll
    for (int j = 0; j < NCH256; ++j) {
        const int idx = j * 256 + tid;
        const int row = idx >> 5, c = idx & 31;
        CP16(g + row * 256 + ((c ^ (row & 7)) << 3),
             s + ((j * 256 + wave * 64) << 3));
    }
}
// ---- staging: attn K tile (fp8, 64 keys x 256 B, global pre-swizzled) ------
static __device__ __forceinline__ void stage_k(const u8* __restrict__ g,
                                               u8* s, int tid) {
    const int wave = tid >> 6;
#pragma unroll
    for (int j = 0; j < 4; ++j) {
        const int idx = j * 256 + tid;
        CP16(g + (idx << 4), s + ((j * 256 + wave * 64) << 4));
    }
}
// ---- staging: attn V tile (fp8, 256 e x 64 keys, global pre-swizzled) ------
static __device__ __forceinline__ void stage_v(const u8* __restrict__ g,
                                               u8* s, int tid) {
    const int wave = tid >> 6;
#pragma unroll
    for (int j = 0; j < 4; ++j) {
        const int idx = j * 256 + tid;
        CP16(g + ((idx >> 2) * 4096) + ((idx & 3) << 4),
             s + ((j * 256 + wave * 64) << 4));
    }
}

// ---------------- fp32 -> bf16 weight conversion (6 x 65536) ----------------
__global__ __launch_bounds__(256) void cvt_w_kernel(
    const float* __restrict__ w0, const float* __restrict__ w1,
    const float* __restrict__ w2, const float* __restrict__ w3,
    const float* __restrict__ w4, const float* __restrict__ w5,
    short* __restrict__ wb)
{
    const int idx = (blockIdx.x * 256 + threadIdx.x) * 8;   // grid 192 -> exact
    const int w = idx >> 16, off = idx & 65535;
    const float* src = w0;
    if (w == 1) src = w1;
    else if (w == 2) src = w2;
    else if (w == 3) src = w3;
    else if (w == 4) src = w4;
    else if (w == 5) src = w5;
    *reinterpret_cast<bf16x8*>(wb + w * 65536 + off) = ldA8(src + off);
}

// ---------------- QKV projection (bf16 MFMA), fp8 outputs, un-fused ---------
// grid (256, 3): x = 64-row token tile, y = {Q,K,V}. 3 concurrent blocks/CU.
// Q pre-scaled by log2(e); K and V written in the attn-LDS layouts.
template <typename TX>
__global__ __launch_bounds__(256, 2) void qkv_proj_kernel(
    const TX* __restrict__ X, const short* __restrict__ Wb,
    const float* __restrict__ bq, const float* __restrict__ bk,
    const float* __restrict__ bv,
    u8* __restrict__ Qo, u8* __restrict__ Ko, u8* __restrict__ VTo)
{
    __shared__ __attribute__((aligned(16))) short Wt[128 * 256];  // 64 KB half
    const int tid  = threadIdx.x;
    const int lane = tid & 63;
    const int wave = tid >> 6;
    const int c16  = lane & 15;
    const int quad = lane >> 4;
    const int which = blockIdx.y;
    const int m0 = blockIdx.x * 64 + wave * 16;

    const short* W    = Wb + which * 65536;
    const float* bias = (which == 0) ? bq : (which == 1) ? bk : bv;

    bf16x8 a[8];
#pragma unroll
    for (int ke = 0; ke < 8; ++ke)
        a[ke] = ldA8(X + (m0 + c16) * 256 + ke * 32 + quad * 8);

    f32x4 acc[16];
#pragma unroll
    for (int nb = 0; nb < 16; ++nb) { f32x4 z = {0.f, 0.f, 0.f, 0.f}; acc[nb] = z; }

#pragma unroll
    for (int half = 0; half < 2; ++half) {
        if (half) __syncthreads();
        stage_rows<16>(W + half * 128 * 256, Wt, tid);
        __syncthreads();
#pragma unroll
        for (int nb8 = 0; nb8 < 8; ++nb8) {
            const int nb = half * 8 + nb8;
            const short* wr = Wt + (nb8 * 16 + c16) * 256;
#pragma unroll
            for (int ke = 0; ke < 8; ++ke) {
                bf16x8 b = *reinterpret_cast<const bf16x8*>(
                    wr + (((ke * 4 + quad) ^ (c16 & 7)) << 3));
                acc[nb] = MFMA_BF16(a[ke], b, acc[nb]);
            }
        }
    }

    if (which == 0) {
        // Q: byte-linear [token][e], pre-scaled by log2(e)
        constexpr float L2E = 1.4426950408889634f;
#pragma unroll
        for (int nb = 0; nb < 16; ++nb) {
            const int o = nb * 16 + c16;
            const float bb_ = bias[o];
#pragma unroll
            for (int r = 0; r < 4; ++r)
                Qo[(m0 + quad * 4 + r) * 256 + o] = f2fp8((acc[nb][r] + bb_) * L2E);
        }
    } else if (which == 1) {
        // K: 16B unit u=o>>4 of key row stored at position u^(row&15)
#pragma unroll
        for (int nb = 0; nb < 16; ++nb) {
            const int o = nb * 16 + c16;   // o>>4 = nb, o&15 = c16
            const float bb_ = bias[o];
#pragma unroll
            for (int r = 0; r < 4; ++r) {
                const int row = m0 + quad * 4 + r;
                Ko[row * 256 + (((nb ^ (row & 15)) << 4) | c16)] =
                    f2fp8(acc[nb][r] + bb_);
            }
        }
    } else {
        // V^T: [e][4096 keys]; within each 64-key group, 16B unit
        // j=(n>>4)&3 stored at slot (j^((o>>1)&3))
#pragma unroll
        for (int nb = 0; nb < 16; ++nb) {
            const int o = nb * 16 + c16;
            const float bb_ = bias[o];
            const int row = m0 + quad * 4;
            const int batch = row >> 12;
            const int n = row & 4095;
            const int nsw = (n & ~63) | ((((n >> 4) ^ (o >> 1)) & 3) << 4) |
                            (n & 12);
            unsigned int pk = pk4fp8(acc[nb][0] + bb_, acc[nb][1] + bb_,
                                     acc[nb][2] + bb_, acc[nb][3] + bb_);
            *reinterpret_cast<unsigned int*>(
                VTo + (size_t)batch * (256 * 4096) + o * 4096 + nsw) = pk;
        }
    }
}

// ---------------- split-K flash attention partial (MX-fp8 32x32x64) ---------
// grid 512: combo = ((bi&7)<<1)|(bi>>8) -> 2 (batch,ks) pairs per XCD;
// qt = (bi>>3)&31. Block 256 thr = 4 waves x 32 q-rows; BK=64, 16 iters;
// K,V fp8 double-buffered in LDS (64 KB). 2 blocks/CU, 2 waves/SIMD.
// Pipeline (r14): softmax(kt) overlaps S^T(kt)'s MFMA drain; per iter
// [softmax | PV | barrier | stage(kt+2) | S^T(kt+1)].
__global__ __launch_bounds__(256, 2) void attn_part_kernel(
    const u8* __restrict__ Qb, const u8* __restrict__ Kb,
    const u8* __restrict__ VTb,
    short* __restrict__ Op, float* __restrict__ Lo)
{
    __shared__ __attribute__((aligned(16))) u8 Kt[2][64 * 256];   // 2x16 KB
    __shared__ __attribute__((aligned(16))) u8 Vt[2][256 * 64];   // 2x16 KB

    const int tid  = threadIdx.x;
    const int lane = tid & 63;
    const int wave = tid >> 6;
    const int l31  = lane & 31;
    const int hi   = lane >> 5;
    const int c16  = lane & 15;
    const int bi = blockIdx.x;
    const int combo = ((bi & 7) << 1) | (bi >> 8);
    const int batch = combo >> 2;
    const int ks    = combo & 3;
    const int qt    = (bi >> 3) & 31;
    const size_t bb = (size_t)batch * (4096 * 256);
    const int rw = qt * 128 + wave * 32;          // wave's 32 q rows
    const int kbase = ks * 1024;

    // Q fragments (B operand): Q[q=l31][e = ke*64 + hi*32 + 0..31]
    i32x8 qf[4];
#pragma unroll
    for (int ke = 0; ke < 4; ++ke) {
        const u8* qp = Qb + bb + (rw + l31) * 256 + ke * 64 + hi * 32;
        qf[ke] = cat(*reinterpret_cast<const i32x4*>(qp),
                     *reinterpret_cast<const i32x4*>(qp + 16));
    }

    f32x16 z16;
#pragma unroll
    for (int i = 0; i < 16; ++i) z16[i] = 0.f;
    f32x16 oa[8];
#pragma unroll
    for (int et = 0; et < 8; ++et) oa[et] = z16;
    f32x16 lacc = z16;                 // row-sums via ones-MFMA

    i32x8 onesf;                       // fp8 e4m3 1.0 = 0x38, splat
#pragma unroll
    for (int i = 0; i < 8; ++i) onesf[i] = 0x38383838;

    // lane-constant LDS read offsets (all 2-way max per quarter-wave = free)
    int kx0[4], kx1[4];
#pragma unroll
    for (int ke = 0; ke < 4; ++ke) {
        kx0[ke] = ((ke * 4 + hi * 2) ^ c16) << 4;
        kx1[ke] = ((ke * 4 + hi * 2 + 1) ^ c16) << 4;
    }
    const int vsw = (l31 >> 1) & 3;
    const int vx0 = ((hi * 2) ^ vsw) << 4;
    const int vx1 = ((hi * 2 + 1) ^ vsw) << 4;

    const u8* Kg = Kb + bb + kbase * 256;
    const u8* Vg = VTb + bb + kbase;

    f32x16 s0, s1;
    auto compute_st = [&](const u8* K) {
        const u8* kp = K + l31 * 256;
        s0 = z16; s1 = z16;
        __builtin_amdgcn_s_setprio(1);
#pragma unroll
        for (int ke = 0; ke < 4; ++ke) {
            i32x8 a0 = cat(*reinterpret_cast<const i32x4*>(kp + kx0[ke]),
                           *reinterpret_cast<const i32x4*>(kp + kx1[ke]));
            s0 = MFMA_SC(a0, qf[ke], s0, SCALE_1, SCALE_Q);
            i32x8 a1 = cat(*reinterpret_cast<const i32x4*>(kp + 8192 + kx0[ke]),
                           *reinterpret_cast<const i32x4*>(kp + 8192 + kx1[ke]));
            s1 = MFMA_SC(a1, qf[ke], s1, SCALE_1, SCALE_Q);
        }
        __builtin_amdgcn_s_setprio(0);
    };

    // ---- prologue: stage tile 0, S^T(0), issue stage tile 1 ----
    stage_k(Kg, &Kt[0][0], tid);
    stage_v(Vg, &Vt[0][0], tid);
    __syncthreads();
    compute_st(&Kt[0][0]);
    stage_k(Kg + 64 * 256, &Kt[1][0], tid);
    stage_v(Vg + 64, &Vt[1][0], tid);

    for (int kt = 0; kt < 16; ++kt) {
        // ---- softmax(kt): p = exp2(s); pack to fp8 dwords per tile ----
        // (overlaps S^T(kt)'s trailing MFMAs issued before the last barrier)
        unsigned int dw0[4], dw1[4];
#pragma unroll
        for (int g = 0; g < 4; ++g) {
            const float p00 = fexp2(s0[4 * g + 0]);
            const float p01 = fexp2(s0[4 * g + 1]);
            const float p02 = fexp2(s0[4 * g + 2]);
            const float p03 = fexp2(s0[4 * g + 3]);
            const float p10 = fexp2(s1[4 * g + 0]);
            const float p11 = fexp2(s1[4 * g + 1]);
            const float p12 = fexp2(s1[4 * g + 2]);
            const float p13 = fexp2(s1[4 * g + 3]);
            dw0[g] = pk4fp8(p00, p01, p02, p03);
            dw1[g] = pk4fp8(p10, p11, p12, p13);
        }
        // assemble PV A-frag: lane hi needs ALL 8 dwords of tile hi
#pragma unroll
        for (int g = 0; g < 4; ++g)
            asm volatile("v_permlane32_swap_b32 %0, %1"
                         : "+v"(dw0[g]), "+v"(dw1[g]));
        i32x8 pf;
        pf[0] = (int)dw0[0]; pf[1] = (int)dw1[0];
        pf[2] = (int)dw0[1]; pf[3] = (int)dw1[1];
        pf[4] = (int)dw0[2]; pf[5] = (int)dw1[2];
        pf[6] = (int)dw0[3]; pf[7] = (int)dw1[3];

        // ---- PV(kt): O += P V, 8 e-tiles of 32; + row-sum via ones-B ----
        {
            const u8* V = &Vt[kt & 1][0];
            __builtin_amdgcn_s_setprio(1);
#pragma unroll
            for (int et = 0; et < 8; ++et) {
                const u8* vp = V + (et * 32 + l31) * 64;
                i32x8 b = cat(*reinterpret_cast<const i32x4*>(vp + vx0),
                              *reinterpret_cast<const i32x4*>(vp + vx1));
                oa[et] = MFMA_SC(pf, b, oa[et], SCALE_1, SCALE_1);
            }
            lacc = MFMA_SC(pf, onesf, lacc, SCALE_1, SCALE_1);
            __builtin_amdgcn_s_setprio(0);
        }

        if (kt < 15) {
            __syncthreads();          // tile kt+1 ready; all readers of buf
                                      // kt&1 (PV kt) are done
            if (kt < 14) {            // stage tile kt+2 into freed buffer
                stage_k(Kg + (kt + 2) * 64 * 256, &Kt[kt & 1][0], tid);
                stage_v(Vg + (kt + 2) * 64, &Vt[kt & 1][0], tid);
            }
            compute_st(&Kt[(kt + 1) & 1][0]);   // S^T(kt+1); next iter's
                                                // softmax overlaps these
        }
    }

    // ---- epilogue: write O partial + l (from lacc; cols are redundant) ----
    const size_t base = (size_t)ks * 16384 + batch * 4096 + rw;
#pragma unroll
    for (int et = 0; et < 8; ++et)
#pragma unroll
        for (int r = 0; r < 16; ++r) {
            const int qr = (r & 3) + 8 * (r >> 2) + 4 * hi;
            Op[(base + qr) * 256 + et * 32 + l31] = f2bf(oa[et][r]);
        }
    if (l31 == 0) {
#pragma unroll
        for (int r = 0; r < 16; ++r) {
            const int qr = (r & 3) + 8 * (r >> 2) + 4 * hi;
            Lo[base + qr] = lacc[r];
        }
    }
}

// ---------------- merge splits + residual + LayerNorm ----------------
template <typename TRES, typename TOUT>
__global__ __launch_bounds__(256) void merge_ln_kernel(
    const short* __restrict__ Op, const float* __restrict__ Lo,
    const TRES* __restrict__ res, const float* __restrict__ gamma,
    const float* __restrict__ beta, TOUT* __restrict__ out)
{
    const int lane = threadIdx.x & 63;
    const int wave = threadIdx.x >> 6;
    const int row = blockIdx.x * 4 + wave;          // batch*4096 + local row
    const float li = 1.0f / (Lo[row] + Lo[16384 + row] +
                             Lo[32768 + row] + Lo[49152 + row]);
    const int e = lane * 4;
    float o[4] = {0.f, 0.f, 0.f, 0.f};
#pragma unroll
    for (int s = 0; s < 4; ++s) {
        ushort4 u = *reinterpret_cast<const ushort4*>(
            Op + ((size_t)s * 16384 + row) * 256 + e);
        o[0] += bf2f((short)u.x);
        o[1] += bf2f((short)u.y);
        o[2] += bf2f((short)u.z);
        o[3] += bf2f((short)u.w);
    }
    float y[4];
#pragma unroll
    for (int i = 0; i < 4; ++i)
        y[i] = o[i] * li + ld1(res + (size_t)row * 256 + e + i);

    float sum = y[0] + y[1] + y[2] + y[3];
    float sq  = y[0]*y[0] + y[1]*y[1] + y[2]*y[2] + y[3]*y[3];
#pragma unroll
    for (int d = 1; d < 64; d <<= 1) {
        sum += __shfl_xor(sum, d, 64);
        sq  += __shfl_xor(sq,  d, 64);
    }
    const float mean = sum * (1.0f / 256.0f);
    const float var  = sq * (1.0f / 256.0f) - mean * mean;
    const float rstd = rsqrtf(var + 1e-5f);
#pragma unroll
    for (int i = 0; i < 4; ++i)
        st1(out + (size_t)row * 256 + e + i,
            (y[i] - mean) * rstd * gamma[e + i] + beta[e + i]);
}

extern "C" void kernel_launch(void* const* d_in, const int* in_sizes, int n_in,
                              void* d_out, int out_size, void* d_ws, size_t ws_size,
                              hipStream_t stream) {
    const float* x   = (const float*)d_in[0];
    const float* Wq1 = (const float*)d_in[1];
    const float* bq1 = (const float*)d_in[2];
    const float* Wk1 = (const float*)d_in[3];
    const float* bk1 = (const float*)d_in[4];
    const float* Wv1 = (const float*)d_in[5];
    const float* bv1 = (const float*)d_in[6];
    const float* Wq2 = (const float*)d_in[7];
    const float* bq2 = (const float*)d_in[8];
    const float* Wk2 = (const float*)d_in[9];
    const float* bk2 = (const float*)d_in[10];
    const float* Wv2 = (const float*)d_in[11];
    const float* bv2 = (const float*)d_in[12];
    const float* g1  = (const float*)d_in[13];
    const float* be1 = (const float*)d_in[14];
    const float* g2  = (const float*)d_in[15];
    const float* be2 = (const float*)d_in[16];

    const size_t NE = (size_t)16384 * 256;   // 4,194,304
    short* O1  = (short*)d_ws;               // 8 MB (layer-1 output, bf16)
    short* Wb  = O1 + NE;                    // 6 x 65536 bf16
    u8*    Qb  = (u8*)(Wb + 6 * 65536);      // fp8, 4 MB
    u8*    Kb  = Qb + NE;                    // fp8, 4 MB
    u8*    VTb = Kb + NE;                    // fp8, 4 MB
    short* Op  = (short*)(VTb + NE);         // 4 x 16384 x 256 bf16 = 32 MB
    float* Lo  = (float*)(Op + 4 * NE);      // 4 x 16384 fp32
    float* outp = (float*)d_out;

    dim3 pgrid(256, 3), pblk(256);

    cvt_w_kernel<<<192, 256, 0, stream>>>(Wq1, Wk1, Wv1, Wq2, Wk2, Wv2, Wb);

    qkv_proj_kernel<float><<<pgrid, pblk, 0, stream>>>(
        x, Wb, bq1, bk1, bv1, Qb, Kb, VTb);
    attn_part_kernel<<<512, 256, 0, stream>>>(Qb, Kb, VTb, Op, Lo);
    merge_ln_kernel<float, short><<<4096, 256, 0, stream>>>(Op, Lo, x, g1, be1, O1);

    qkv_proj_kernel<short><<<pgrid, pblk, 0, stream>>>(
        O1, Wb + 3 * 65536, bq2, bk2, bv2, Qb, Kb, VTb);
    attn_part_kernel<<<512, 256, 0, stream>>>(Qb, Kb, VTb, Op, Lo);
    merge_ln_kernel<short, float><<<4096, 256, 0, stream>>>(Op, Lo, O1, g2, be2, outp);
}